// Round 7
// baseline (222.118 us; speedup 1.0000x reference)
//
#include <hip/hip_runtime.h>

typedef unsigned short u16;
typedef unsigned int u32;
typedef __bf16 bf16x8 __attribute__((ext_vector_type(8)));
typedef float f32x4 __attribute__((ext_vector_type(4)));

#define L_SEQ 2048
#define NH 16
#define DH 64
#define D_MODEL 1024
// shift in exp2 domain: 10*log2(e); q pre-scaled by 0.125*log2(e)
#define ATT_SHIFT2 14.426950408889634f
#define QSCALE_LOG2E 0.18033688011112042f  // 0.125 * log2(e)

__device__ __forceinline__ u16 f2bf(float f) {
  union { float f; u32 u; } v; v.f = f;
  u32 u = v.u;
  return (u16)((u + 0x7fffu + ((u >> 16) & 1u)) >> 16);  // RNE
}
__device__ __forceinline__ float bf2f(u16 b) {
  union { u32 u; float f; } v; v.u = ((u32)b) << 16;
  return v.f;
}
// pack two floats -> two bf16 (round-half-up), lo_val in low 16 bits
__device__ __forceinline__ u32 pk2(float lo_val, float hi_val) {
  union { float f; u32 u; } a, b;
  a.f = hi_val; b.f = lo_val;
  return __builtin_amdgcn_perm(a.u + 0x8000u, b.u + 0x8000u, 0x07060302u);
}
// truncating pack (1 inst) — used for P where values are in [0,1]
__device__ __forceinline__ u32 pk2t(float lo_val, float hi_val) {
  union { float f; u32 u; } a, b;
  a.f = hi_val; b.f = lo_val;
  return __builtin_amdgcn_perm(a.u, b.u, 0x07060302u);
}
__device__ __forceinline__ bf16x8 ld8(const u16* p) {
  union { uint4 u; bf16x8 b; } v;
  v.u = *(const uint4*)p;
  return v.b;
}
__device__ __forceinline__ f32x4 fzero4() { f32x4 z = {0.f, 0.f, 0.f, 0.f}; return z; }

__device__ __forceinline__ float fexp2(float x) {
#if __has_builtin(__builtin_amdgcn_exp2f)
  return __builtin_amdgcn_exp2f(x);
#else
  return __expf(x * 0.6931471805599453f);
#endif
}

// async global->LDS: lane i of the wave writes ldsbase + i*16
__device__ __forceinline__ void gll16(const u16* g, u16* l) {
  __builtin_amdgcn_global_load_lds((const __attribute__((address_space(1))) u32*)g,
                                   (__attribute__((address_space(3))) u32*)l, 16, 0, 0);
}

// ---------------- K1: fused fp32 -> bf16 cast of x, w_qkv, w_proj ----------------
__global__ __launch_bounds__(256) void cvt_all(const float* __restrict__ x,
                                               const float* __restrict__ wqkv,
                                               const float* __restrict__ wproj,
                                               u16* __restrict__ xb,
                                               u16* __restrict__ wqkvb,
                                               u16* __restrict__ wprojb) {
  int i = blockIdx.x * 256 + threadIdx.x;  // 0 .. 2097151 float4s
  const float* s;
  u16* d;
  int off;
  if (i < 1048576)      { s = x;     d = xb;     off = i; }
  else if (i < 1835008) { s = wqkv;  d = wqkvb;  off = i - 1048576; }
  else                  { s = wproj; d = wprojb; off = i - 1835008; }
  float4 v = ((const float4*)s)[off];
  ((ushort4*)d)[off] = make_ushort4(f2bf(v.x), f2bf(v.y), f2bf(v.z), f2bf(v.w));
}

// ---------------- K2: QKV GEMM with fused RMSNorm+RoPE / v-transpose epilogue ----
// C[4096,3072] = x * w_qkv^T. 128x128 tile, BK=64, m97 staging.
// q/k tiles: rmsnorm (f32 acc) + rope + (q: scale) in-epilogue, written to
// (B,H,L,Dh). v tiles: LDS-transposed to (B,H,Dh,L).
__global__ __launch_bounds__(256) void gemm_qkv(const u16* __restrict__ A,
                                                const u16* __restrict__ B,
                                                const float* __restrict__ rope,
                                                const float* __restrict__ qw,
                                                const float* __restrict__ kw,
                                                u16* __restrict__ qb,
                                                u16* __restrict__ kb,
                                                u16* __restrict__ vtb) {
  __shared__ u16 smem[16384];  // As=[0:8192), Bs=[8192:16384); reused for v-transpose
  u16* As = smem;
  u16* Bs = smem + 8192;
  const int t = threadIdx.x;
  const int lane = t & 63, wv = t >> 6;
  const int col = lane & 15, quad = lane >> 4;
  const int wr = wv >> 1, wc = wv & 1;
  const int m0 = blockIdx.y * 128, n0 = blockIdx.x * 128;

  f32x4 acc[4][4];
#pragma unroll
  for (int i = 0; i < 4; ++i)
#pragma unroll
    for (int j = 0; j < 4; ++j) acc[i][j] = fzero4();

  for (int kt = 0; kt < 1024; kt += 64) {
    __syncthreads();
#pragma unroll
    for (int it = 0; it < 4; ++it) {
      int id0 = it * 256 + wv * 64;  // wave-uniform LDS base (16B units)
      int id = id0 + lane;
      int row = id >> 3, cs = id & 7;
      int csrc = cs ^ (row & 7);     // XOR swizzle
      gll16(A + (size_t)(m0 + row) * 1024 + kt + csrc * 8, As + (size_t)id0 * 8);
      gll16(B + (size_t)(n0 + row) * 1024 + kt + csrc * 8, Bs + (size_t)id0 * 8);
    }
    __syncthreads();
#pragma unroll
    for (int c = 0; c < 2; ++c) {
      bf16x8 af[4], bfv[4];
#pragma unroll
      for (int f = 0; f < 4; ++f) {
        int r = wr * 64 + f * 16 + col;
        af[f] = ld8(&As[(r * 8 + ((c * 4 + quad) ^ (r & 7))) * 8]);
        int rb = wc * 64 + f * 16 + col;
        bfv[f] = ld8(&Bs[(rb * 8 + ((c * 4 + quad) ^ (rb & 7))) * 8]);
      }
#pragma unroll
      for (int i = 0; i < 4; ++i)
#pragma unroll
        for (int j = 0; j < 4; ++j)
          acc[i][j] = __builtin_amdgcn_mfma_f32_16x16x32_bf16(af[i], bfv[j], acc[i][j], 0, 0, 0);
    }
  }

  const int region = n0 >> 10;  // 0=q, 1=k, 2=v (block-uniform)
  if (region < 2) {
    // fused RMSNorm + RoPE. head = (n0&1023)/64 + wc; dh = j*16+col.
    const float* w = region ? kw : qw;
    u16* dst = region ? kb : qb;
    const float scale = region ? 1.0f : QSCALE_LOG2E;
    const int h = ((n0 & 1023) >> 6) + wc;
    float wloc[4];
#pragma unroll
    for (int j = 0; j < 4; ++j) wloc[j] = w[j * 16 + col];
#pragma unroll
    for (int i = 0; i < 4; ++i) {
#pragma unroll
      for (int r = 0; r < 4; ++r) {
        float v0 = acc[i][0][r], v1 = acc[i][1][r], v2 = acc[i][2][r], v3 = acc[i][3][r];
        float ss = v0 * v0 + v1 * v1 + v2 * v2 + v3 * v3;
        ss += __shfl_xor(ss, 1); ss += __shfl_xor(ss, 2);
        ss += __shfl_xor(ss, 4); ss += __shfl_xor(ss, 8);
        float inv = rsqrtf(ss * (1.f / 64.f) + 1e-6f);
        int gr = m0 + wr * 64 + i * 16 + quad * 4 + r;
        int b = gr >> 11, l = gr & 2047;
        const float2* rope2 = (const float2*)rope + (size_t)l * 32;
        size_t obase = ((size_t)(b * NH + h) * L_SEQ + l) * DH;
        float vv[4] = {v0, v1, v2, v3};
#pragma unroll
        for (int j = 0; j < 4; ++j) {
          float val = vv[j] * inv * wloc[j];
          float part = __shfl_xor(val, 1);
          float2 cs = rope2[j * 8 + (col >> 1)];
          float outv = (lane & 1) ? (part * cs.y + val * cs.x)
                                  : (val * cs.x - part * cs.y);
          dst[obase + j * 16 + col] = f2bf(outv * scale);
        }
      }
    }
  } else {
    // v: transpose the 128x128 C tile through LDS, write dh-major rows
    __syncthreads();  // all waves done reading As/Bs
#pragma unroll
    for (int i = 0; i < 4; ++i) {
      int m_l = wr * 64 + i * 16 + quad * 4;
#pragma unroll
      for (int j = 0; j < 4; ++j) {
        int n_l = wc * 64 + j * 16 + col;
        int ta = n_l * 128 + (m_l ^ ((n_l & 15) << 3));
        *(uint2*)(smem + ta) = make_uint2(pk2(acc[i][j][0], acc[i][j][1]),
                                          pk2(acc[i][j][2], acc[i][j][3]));
      }
    }
    __syncthreads();
    const int b = m0 >> 11, lbase = m0 & 2047;
    const int n_l = t >> 1, mh = (t & 1) * 64;
    const int gc = (n0 - 2048) + n_l;
    const int h = gc >> 6, dh = gc & 63;
    u16* vrow = vtb + ((size_t)(b * NH + h) * DH + dh) * L_SEQ + lbase + mh;
#pragma unroll
    for (int c2 = 0; c2 < 8; ++c2) {
      int m = mh + c2 * 8;
      uint4 v = *(const uint4*)(smem + n_l * 128 + (m ^ ((n_l & 15) << 3)));
      *(uint4*)(vrow + c2 * 8) = v;
    }
  }
}

// ---------------- K3: flash attention — barrier-free register streaming ----------
// Wave = 64 q rows (4 frags). NO LDS staging of K/V: fragments stream from L2/L1
// via coalesced global loads (VMEM pipe), software-pipelined (vreg issued at tile
// top, kreg for tile tt+1 issued before PV). Only the P C->A round-trip uses LDS
// (wave-private, no barriers anywhere). Grid x = qy*64 + (bh*2+half) so x%8 (XCD)
// is fixed per (bh,half): 8 halves x 256KB = 2MB per XCD L2, all consumers
// co-resident on that XCD.
__global__ __launch_bounds__(256, 2) void attn_flash(const u16* __restrict__ qb,
                                                     const u16* __restrict__ kb,
                                                     const u16* __restrict__ vtb,
                                                     u16* __restrict__ po,
                                                     float* __restrict__ pl) {
  __shared__ u16 ldsP[16384];   // per-wave P: 64 q-rows x 64 keys, slot-swizzled
  const int t = threadIdx.x;
  const int lane = t & 63, wv = t >> 6;
  const int col = lane & 15, quad = lane >> 4;
  const int bhh = blockIdx.x & 63;
  const int bh = bhh >> 1;
  const int half = bhh & 1;
  const int q0 = (blockIdx.x >> 6) * 256 + wv * 64;

  const u16* kbase = kb + ((size_t)bh * L_SEQ + half * 1024) * DH;
  const u16* vbase = vtb + (size_t)bh * DH * L_SEQ + half * 1024;

  bf16x8 qfrag[4][2];
#pragma unroll
  for (int qf = 0; qf < 4; ++qf)
#pragma unroll
    for (int c = 0; c < 2; ++c)
      qfrag[qf][c] = ld8(qb + ((size_t)bh * L_SEQ + q0 + qf * 16 + col) * DH + c * 32 + quad * 8);

  f32x4 o[4][4];
#pragma unroll
  for (int qf = 0; qf < 4; ++qf)
#pragma unroll
    for (int nf = 0; nf < 4; ++nf) o[qf][nf] = fzero4();
  float lrow[4] = {0.f, 0.f, 0.f, 0.f};

  u16* pb = &ldsP[wv * 4096];
  const int kc_w = (quad >> 1);      // write sub-chunk select
  const int sub = (quad & 1) * 4;    // u16 offset within 16B slot

  bf16x8 kreg[8], vreg[8];
  // prefetch K tile 0: K[key = mf*16+col][dh = c*32 + quad*8 ..]
#pragma unroll
  for (int mf = 0; mf < 4; ++mf)
#pragma unroll
    for (int c = 0; c < 2; ++c)
      kreg[mf * 2 + c] = ld8(kbase + (size_t)(mf * 16 + col) * DH + c * 32 + quad * 8);

  for (int tt = 0; tt < 16; ++tt) {
    const int kt = tt * 64;
    // issue V loads for this tile (consumed at PV, ~whole QK phase later)
#pragma unroll
    for (int nf = 0; nf < 4; ++nf)
#pragma unroll
      for (int c = 0; c < 2; ++c)
        vreg[nf * 2 + c] = ld8(vbase + (size_t)(nf * 16 + col) * L_SEQ + kt + c * 32 + quad * 8);

    // S^T = K Q^T, one key-frag (mf) at a time; kreg shared across 4 q-frags
#pragma unroll
    for (int mf = 0; mf < 4; ++mf) {
      f32x4 s[4];
#pragma unroll
      for (int qf = 0; qf < 4; ++qf) {
        s[qf] = __builtin_amdgcn_mfma_f32_16x16x32_bf16(kreg[mf * 2 + 0], qfrag[qf][0], fzero4(), 0, 0, 0);
        s[qf] = __builtin_amdgcn_mfma_f32_16x16x32_bf16(kreg[mf * 2 + 1], qfrag[qf][1], s[qf], 0, 0, 0);
      }
      const int kc = mf * 2 + kc_w;  // key-chunk (8 keys) index
#pragma unroll
      for (int qf = 0; qf < 4; ++qf) {
        float e0 = fexp2(s[qf][0] - ATT_SHIFT2);
        float e1 = fexp2(s[qf][1] - ATT_SHIFT2);
        float e2 = fexp2(s[qf][2] - ATT_SHIFT2);
        float e3 = fexp2(s[qf][3] - ATT_SHIFT2);
        lrow[qf] += (e0 + e1) + (e2 + e3);
        const int q = qf * 16 + col;
        const int slot = q * 8 + (kc ^ (q & 7));
        *(uint2*)(pb + slot * 8 + sub) = make_uint2(pk2t(e0, e1), pk2t(e2, e3));
      }
    }

    // prefetch K tile tt+1 (stays in flight across the PV phase)
    if (tt < 15) {
      const int kn = kt + 64;
#pragma unroll
      for (int mf = 0; mf < 4; ++mf)
#pragma unroll
        for (int c = 0; c < 2; ++c)
          kreg[mf * 2 + c] = ld8(kbase + (size_t)(kn + mf * 16 + col) * DH + c * 32 + quad * 8);
    }

    // O += P V : vreg shared across all 4 q-frags
#pragma unroll
    for (int c = 0; c < 2; ++c) {
      bf16x8 pa[4];
#pragma unroll
      for (int qf = 0; qf < 4; ++qf) {
        const int q = qf * 16 + col;
        pa[qf] = ld8(pb + (q * 8 + ((c * 4 + quad) ^ (q & 7))) * 8);
      }
#pragma unroll
      for (int nf = 0; nf < 4; ++nf)
#pragma unroll
        for (int qf = 0; qf < 4; ++qf)
          o[qf][nf] = __builtin_amdgcn_mfma_f32_16x16x32_bf16(pa[qf], vreg[nf * 2 + c], o[qf][nf], 0, 0, 0);
    }
  }

  // epilogue: finish l reduction, write unnormalized partials
  u16* pob = po + (size_t)(half * 32 + bh) * L_SEQ * DH;
#pragma unroll
  for (int qf = 0; qf < 4; ++qf) {
    lrow[qf] += __shfl_xor(lrow[qf], 16);
    lrow[qf] += __shfl_xor(lrow[qf], 32);
    if (quad == 0)
      pl[(size_t)(half * 32 + bh) * L_SEQ + q0 + qf * 16 + col] = lrow[qf];
#pragma unroll
    for (int nf = 0; nf < 4; ++nf)
#pragma unroll
      for (int r = 0; r < 4; ++r)
        pob[(size_t)(q0 + qf * 16 + quad * 4 + r) * DH + nf * 16 + col] = f2bf(o[qf][nf][r]);
  }
}

// ---------------- K4: proj GEMM with fused split-K combine ----------------
// out[4096,1024] = combined(po)/l * w_proj^T. BM=64, BN=128, BK=64.
__global__ __launch_bounds__(256) void gemm2_cmb(const u16* __restrict__ po,
                                                 const float* __restrict__ pl,
                                                 const u16* __restrict__ B,
                                                 float* __restrict__ out) {
  __shared__ u16 As[64 * 64];
  __shared__ u16 Bs[128 * 64];
  const int t = threadIdx.x;
  const int lane = t & 63, wv = t >> 6;
  const int col = lane & 15, quad = lane >> 4;
  const int wr = wv >> 1, wc = wv & 1;
  const int m0 = blockIdx.y * 64, n0 = blockIdx.x * 128;
  const int srow = t >> 2, kc0 = (t & 3) * 2;
  const int m = m0 + srow, bb = m >> 11, ll = m & 2047;

  f32x4 acc[2][4];
#pragma unroll
  for (int i = 0; i < 2; ++i)
#pragma unroll
    for (int j = 0; j < 4; ++j) acc[i][j] = fzero4();

  for (int kt = 0; kt < 1024; kt += 64) {
    __syncthreads();
    {
      int h = kt >> 6;
      size_t lidx = (size_t)(bb * 16 + h) * L_SEQ + ll;
      float inv = 1.0f / (pl[lidx] + pl[65536 + lidx]);
      size_t rowoff = lidx * 64;
#pragma unroll
      for (int i = 0; i < 2; ++i) {
        int kc = kc0 + i;
        uint4 a0 = *(const uint4*)(po + rowoff + kc * 8);
        uint4 a1 = *(const uint4*)(po + 4194304 + rowoff + kc * 8);
        union { uint4 u; u16 s[8]; } ua, ub;
        ua.u = a0; ub.u = a1;
        float r[8];
#pragma unroll
        for (int j = 0; j < 8; ++j) r[j] = (bf2f(ua.s[j]) + bf2f(ub.s[j])) * inv;
        uint4 pk = make_uint4(pk2(r[0], r[1]), pk2(r[2], r[3]), pk2(r[4], r[5]), pk2(r[6], r[7]));
        int slot = srow * 8 + (kc ^ (srow & 7));
        *(uint4*)(As + slot * 8) = pk;
      }
    }
#pragma unroll
    for (int it = 0; it < 4; ++it) {
      int id0 = it * 256 + wv * 64;
      int id = id0 + lane;
      int row = id >> 3, cs = id & 7, csrc = cs ^ (row & 7);
      gll16(B + (size_t)(n0 + row) * 1024 + kt + csrc * 8, Bs + (size_t)id0 * 8);
    }
    __syncthreads();
#pragma unroll
    for (int c = 0; c < 2; ++c) {
      bf16x8 af[2], bfv[4];
#pragma unroll
      for (int f = 0; f < 2; ++f) {
        int r = wr * 32 + f * 16 + col;
        af[f] = ld8(&As[(r * 8 + ((c * 4 + quad) ^ (r & 7))) * 8]);
      }
#pragma unroll
      for (int f = 0; f < 4; ++f) {
        int rb = wc * 64 + f * 16 + col;
        bfv[f] = ld8(&Bs[(rb * 8 + ((c * 4 + quad) ^ (rb & 7))) * 8]);
      }
#pragma unroll
      for (int i = 0; i < 2; ++i)
#pragma unroll
        for (int j = 0; j < 4; ++j)
          acc[i][j] = __builtin_amdgcn_mfma_f32_16x16x32_bf16(af[i], bfv[j], acc[i][j], 0, 0, 0);
    }
  }
#pragma unroll
  for (int i = 0; i < 2; ++i) {
    int gr = m0 + wr * 32 + i * 16 + quad * 4;
#pragma unroll
    for (int j = 0; j < 4; ++j) {
      int gc = n0 + wc * 64 + j * 16 + col;
#pragma unroll
      for (int r = 0; r < 4; ++r)
        out[(size_t)(gr + r) * D_MODEL + gc] = acc[i][j][r];
    }
  }
}

// ---------------- launcher ----------------
extern "C" void kernel_launch(void* const* d_in, const int* in_sizes, int n_in,
                              void* d_out, int out_size, void* d_ws, size_t ws_size,
                              hipStream_t stream) {
  const float* x     = (const float*)d_in[0];
  const float* rope  = (const float*)d_in[1];
  const float* wqkv  = (const float*)d_in[2];
  const float* wproj = (const float*)d_in[3];
  const float* qnw   = (const float*)d_in[4];
  const float* knw   = (const float*)d_in[5];
  float* out = (float*)d_out;
  char* ws = (char*)d_ws;

  u16* xb     = (u16*)(ws + 0);          //  8 MB  bf16 x (4096x1024)
  u16* wqkvb  = (u16*)(ws + 8388608);    //  6 MB  bf16 w_qkv (3072x1024)
  u16* wprojb = (u16*)(ws + 14680064);   //  2 MB  bf16 w_proj (1024x1024)
  u16* qb     = (u16*)(ws + 16777216);   //  8 MB  bf16 q (B,H,L,Dh), normed+roped+scaled
  u16* kb     = (u16*)(ws + 25165824);   //  8 MB  bf16 k (B,H,L,Dh), normed+roped
  u16* vtb    = (u16*)(ws + 33554432);   //  8 MB  bf16 v^T (B,H,Dh,L)
  u16* po     = (u16*)(ws + 41943040);   // 16 MB  bf16 o-partials [half][bh][q][dh]
  float* pl   = (float*)(ws + 58720256); // 512 KB f32 l-partials [half][bh][q]

  cvt_all<<<8192, 256, 0, stream>>>(x, wqkv, wproj, xb, wqkvb, wprojb);

  gemm_qkv<<<dim3(24, 32), 256, 0, stream>>>(xb, wqkvb, rope, qnw, knw, qb, kb, vtb);

  attn_flash<<<512, 256, 0, stream>>>(qb, kb, vtb, po, pl);

  gemm2_cmb<<<dim3(8, 64), 256, 0, stream>>>(po, pl, wprojb, out);
}